// Round 1
// 376.058 us; speedup vs baseline: 1.0877x; 1.0877x over previous
//
#include <hip/hip_runtime.h>

// 2-layer LSTM (H=50, B=4096, T=512, D_in=1) + FC(50->1), fused MFMA, round 15.
//
// = round-14 (gate pre-scaling, merged-rcp cell, f16 weights/h, 1 barrier/iter)
// restructured from 13 symmetric waves to 8 LAYER-SPECIALIZED waves:
//   waves 0-3: all 13 L0 tile-jobs (counts {4,3,3,3}), read only b0,b1
//   waves 4-7: all 13 L1 tile-jobs (counts {3,4,3,3}), read b0..b3
// Rationale (rocprof r14): LDS broadcast of the h-vector scaled with wave
// count (13 waves x 4 ds_read_b128 = 53KB/CU/iter ~ 620cyc, co-bottleneck
// with VALU), while cell-update VALU work scales with job count (26, fixed).
// 8-wave split cuts LDS reads to 24 b128 (-55%), balances per-SIMD update
// load {7,7,6,6} (was {8,6,6,6} -> critical SIMD -12%), and issues all MFMA
// chains before the trans-heavy updates for within-wave ILP at 2 waves/SIMD.
// Barrier counts identical on both paths (514); semantics unchanged.
// B-frag layout (r2-r13-verified): k -> ks=k>>5, lane=((k>>3)&3)*16+n, j=k&7.

#define TT 512
#define HH 50
#define BT 16
#define NTHR 512   // 8 waves
#define L2E 1.44269504f

typedef _Float16 half8 __attribute__((ext_vector_type(8)));
typedef float floatx4 __attribute__((ext_vector_type(4)));

static __device__ __forceinline__ float fexp2(float x) { return __builtin_amdgcn_exp2f(x); }
static __device__ __forceinline__ float frcp(float x)  { return __builtin_amdgcn_rcpf(x); }

// PRE-SCALED cell update: inputs are already s_g*gate (s = -log2e, -log2e,
// -2log2e, -log2e for i,f,g,o), i.e. Ei=exp2(gi') = e^-i etc.
// c' = sig(f)*c + sig(i)*tanh(g) = R*[c*(1+Ei)(1+Eg) + (1-Eg)(1+Ef)],
// R = rcp((1+Ef)(1+Ei)(1+Eg)); h = sig(o)*tanh(c'), c clamped (NaN guard).
static __device__ __forceinline__ float cell_update(float gi, float gf, float gg,
                                                    float go, float& c) {
    float Ei = fexp2(gi);
    float Eg = fexp2(gg);
    float Ef = fexp2(gf);
    float p1 = (1.0f + Ei) * (1.0f + Eg);
    float fe = 1.0f + Ef;
    float R  = frcp(fe * p1);
    c = R * (c * p1 + (1.0f - Eg) * fe);
    float cl = fminf(fmaxf(c, -18.0f), 18.0f);
    float Eo = fexp2(go);
    float Ec = fexp2(cl * (-2.0f * L2E));
    float Ro = frcp((1.0f + Eo) * (1.0f + Ec));
    return (1.0f - Ec) * Ro;
}

#define MFMA(a, b, c) __builtin_amdgcn_mfma_f32_16x16x32_f16((a), (b), (c), 0, 0, 0)

// ---------------- layer-0 waves: NJ tile-jobs, tiles tbase..tbase+NJ-1 ----------------
template<int NJ>
static __device__ __forceinline__ void run_l0(
    int tbase, int ln, _Float16 (*Hf)[2048], const float* xs,
    const float* __restrict__ W_ih0, const float* __restrict__ W_hh0,
    const float* __restrict__ b_ih0, const float* __restrict__ b_hh0)
{
    const int m = ln & 15, q = ln >> 4;
    const float GSC[4] = { -L2E, -L2E, -2.0f * L2E, -L2E };

    half8 a0[NJ][2];
    float cc0[NJ][4], bw0[NJ][4], c[NJ];
    int   widx[NJ];
#pragma unroll
    for (int j = 0; j < NJ; ++j) {
        const int  tau  = tbase + j;
        const int  uA   = 4 * tau + (m >> 2);
        const int  gA   = m & 3;
        const bool rokA = (uA < HH);
        const int  wrow = gA * HH + uA;
        const float sA  = GSC[gA];
#pragma unroll
        for (int ks = 0; ks < 2; ++ks) {
            half8 h8;
#pragma unroll
            for (int jj = 0; jj < 8; ++jj) {
                int k = ks * 32 + q * 8 + jj;
                float w = (rokA && k < HH) ? W_hh0[wrow * HH + k] : 0.f;
                h8[jj] = (_Float16)(sA * w);
            }
            a0[j][ks] = h8;
        }
        const int  uC = 4 * tau + q;     // dummy units 50/51 -> zero-wt K slots
        const bool vC = (uC < HH);
#pragma unroll
        for (int g = 0; g < 4; ++g) {
            int rg = g * HH + (vC ? uC : 0);
            cc0[j][g] = vC ? GSC[g] * (b_ih0[rg] + b_hh0[rg]) : 0.f;
            bw0[j][g] = vC ? GSC[g] * W_ih0[rg] : 0.f;
        }
        const int kh = uC & 63;
        widx[j] = ((kh >> 5) * 64 + ((kh >> 3) & 3) * 16 + m) * 8 + (kh & 7);
        c[j] = 0.f;
    }

    __syncthreads();                       // staging (xs, Hf zero) complete

    // ---- t = 0: h1(0) depends on x only (h=0) -> write buf 1 ----
    {
        const float xv = xs[m];
#pragma unroll
        for (int j = 0; j < NJ; ++j) {
            float h = cell_update(cc0[j][0] + bw0[j][0] * xv, cc0[j][1] + bw0[j][1] * xv,
                                  cc0[j][2] + bw0[j][2] * xv, cc0[j][3] + bw0[j][3] * xv,
                                  c[j]);
            Hf[1][widx[j]] = (_Float16)h;
        }
        __syncthreads();
    }

#define ITER0(ttv, P)                                                       \
    {                                                                       \
        half8 b0 = *(const half8*)&Hf[(P)][(0 * 64 + ln) * 8];              \
        half8 b1 = *(const half8*)&Hf[(P)][(1 * 64 + ln) * 8];              \
        const float xv = xs[(ttv) * BT + m];                                \
        floatx4 acc[NJ];                                                    \
        _Pragma("unroll")                                                   \
        for (int j = 0; j < NJ; ++j) {                                      \
            floatx4 a;                                                      \
            _Pragma("unroll")                                               \
            for (int g = 0; g < 4; ++g) a[g] = cc0[j][g] + bw0[j][g] * xv;  \
            a = MFMA(a0[j][0], b0, a);                                      \
            a = MFMA(a0[j][1], b1, a);                                      \
            acc[j] = a;                                                     \
        }                                                                   \
        _Pragma("unroll")                                                   \
        for (int j = 0; j < NJ; ++j) {                                      \
            float h = cell_update(acc[j][0], acc[j][1], acc[j][2], acc[j][3], c[j]); \
            Hf[(P) ^ 1][widx[j]] = (_Float16)h;                             \
        }                                                                   \
        __syncthreads();                                                    \
    }

    for (int k = 1; k <= 255; ++k) {
        ITER0(2 * k - 1, 1);
        ITER0(2 * k, 0);
    }
    ITER0(511, 1);
    __syncthreads();                       // ttv = 512: L1-only step, barrier match
#undef ITER0
}

// ---------------- layer-1 waves: NJ tile-jobs, tiles tbase..tbase+NJ-1 ----------------
template<int NJ>
static __device__ __forceinline__ void run_l1(
    int tbase, int ln, _Float16 (*Hf)[2048],
    const float* __restrict__ W_ih1, const float* __restrict__ W_hh1,
    const float* __restrict__ b_ih1, const float* __restrict__ b_hh1)
{
    const int m = ln & 15, q = ln >> 4;
    const float GSC[4] = { -L2E, -L2E, -2.0f * L2E, -L2E };

    half8 a1[NJ][4];                       // [W_ih1 | pad | W_hh1 | pad] over K=128
    float cc1[NJ][4], c[NJ];
    int   widx[NJ];
#pragma unroll
    for (int j = 0; j < NJ; ++j) {
        const int  tau  = tbase + j;
        const int  uA   = 4 * tau + (m >> 2);
        const int  gA   = m & 3;
        const bool rokA = (uA < HH);
        const int  wrow = gA * HH + uA;
        const float sA  = GSC[gA];
#pragma unroll
        for (int ks = 0; ks < 4; ++ks) {
            half8 h8;
#pragma unroll
            for (int jj = 0; jj < 8; ++jj) {
                int k = ks * 32 + q * 8 + jj;
                float w = 0.f;
                if (rokA) {
                    if (k < HH)                      w = W_ih1[wrow * HH + k];
                    else if (k >= 64 && k < 64 + HH) w = W_hh1[wrow * HH + (k - 64)];
                }
                h8[jj] = (_Float16)(sA * w);
            }
            a1[j][ks] = h8;
        }
        const int  uC = 4 * tau + q;
        const bool vC = (uC < HH);
#pragma unroll
        for (int g = 0; g < 4; ++g) {
            int rg = g * HH + (vC ? uC : 0);
            cc1[j][g] = vC ? GSC[g] * (b_ih1[rg] + b_hh1[rg]) : 0.f;
        }
        const int kh = uC & 63;
        widx[j] = ((kh >> 5) * 64 + ((kh >> 3) & 3) * 16 + m) * 8 + (kh & 7) + 1024;
        c[j] = 0.f;
    }

    __syncthreads();                       // staging complete
    __syncthreads();                       // t=0 prologue: no L1 work (h2(-1)=0)

#define ITER1(P)                                                            \
    {                                                                       \
        half8 b0 = *(const half8*)&Hf[(P)][(0 * 64 + ln) * 8];              \
        half8 b1 = *(const half8*)&Hf[(P)][(1 * 64 + ln) * 8];              \
        half8 b2 = *(const half8*)&Hf[(P)][(2 * 64 + ln) * 8];              \
        half8 b3 = *(const half8*)&Hf[(P)][(3 * 64 + ln) * 8];              \
        floatx4 acc[NJ];                                                    \
        _Pragma("unroll")                                                   \
        for (int j = 0; j < NJ; ++j) {                                      \
            floatx4 a;                                                      \
            _Pragma("unroll")                                               \
            for (int g = 0; g < 4; ++g) a[g] = cc1[j][g];                   \
            a = MFMA(a1[j][0], b0, a);                                      \
            a = MFMA(a1[j][1], b1, a);                                      \
            a = MFMA(a1[j][2], b2, a);                                      \
            a = MFMA(a1[j][3], b3, a);                                      \
            acc[j] = a;                                                     \
        }                                                                   \
        _Pragma("unroll")                                                   \
        for (int j = 0; j < NJ; ++j) {                                      \
            float h = cell_update(acc[j][0], acc[j][1], acc[j][2], acc[j][3], c[j]); \
            Hf[(P) ^ 1][widx[j]] = (_Float16)h;                             \
        }                                                                   \
        __syncthreads();                                                    \
    }

    for (int k = 1; k <= 255; ++k) {
        ITER1(1);                          // ttv = 2k-1 -> computes t = ttv-1
        ITER1(0);                          // ttv = 2k
    }
    ITER1(1);                              // ttv = 511
    ITER1(0);                              // ttv = 512 -> h2(511) -> buf 1
#undef ITER1
}

__global__ __launch_bounds__(NTHR, 2) void lstm_mfma(
    const float* __restrict__ x,
    const float* __restrict__ W_ih0, const float* __restrict__ W_hh0,
    const float* __restrict__ b_ih0, const float* __restrict__ b_hh0,
    const float* __restrict__ W_ih1, const float* __restrict__ W_hh1,
    const float* __restrict__ b_ih1, const float* __restrict__ b_hh1,
    const float* __restrict__ W_fc,  const float* __restrict__ b_fc,
    float* __restrict__ out)
{
    __shared__ __align__(16) _Float16 Hf[2][2048];   // [buf][(ks*64+lane)*8+j]
    __shared__ float xs[TT * BT];

    const int tid = threadIdx.x;
    const int ln  = tid & 63;
    const int wv  = tid >> 6;              // 0..7
    const int b0g = blockIdx.x * BT;

    // ---------------- one-time staging ----------------
    for (int i = tid; i < BT * TT; i += NTHR) {
        int b = i & 15, t = i >> 4;
        xs[t * BT + b] = x[(size_t)(b0g + b) * TT + t];
    }
    for (int i = tid; i < 2 * 2048; i += NTHR) ((_Float16*)Hf)[i] = (_Float16)0.f;

    // job split: L0 waves {0:4@0, 1:3@4, 2:3@7, 3:3@10}; L1 {4:3@0, 5:4@3, 6:3@7, 7:3@10}
    // -> per-SIMD cell-update load {7,7,6,6}. One call site per instantiation
    // (4 code copies) to bound I$ footprint.
    if (wv == 0)
        run_l0<4>(0, ln, Hf, xs, W_ih0, W_hh0, b_ih0, b_hh0);
    else if (wv < 4)
        run_l0<3>(wv == 1 ? 4 : (wv == 2 ? 7 : 10), ln, Hf, xs, W_ih0, W_hh0, b_ih0, b_hh0);
    else if (wv == 5)
        run_l1<4>(3, ln, Hf, W_ih1, W_hh1, b_ih1, b_hh1);
    else
        run_l1<3>(wv == 4 ? 0 : (wv == 6 ? 7 : 10), ln, Hf, W_ih1, W_hh1, b_ih1, b_hh1);

    // ---------------- FC epilogue: h2(511) in buf 1, slots k = 64+u ----------------
    if (tid < BT) {
        float a = b_fc[0];
        for (int u = 0; u < HH; ++u) {
            int k = 64 + u;
            int idx = ((k >> 5) * 64 + ((k >> 3) & 3) * 16 + tid) * 8 + (k & 7);
            a = fmaf((float)Hf[1][idx], W_fc[u], a);
        }
        out[b0g + tid] = a;
    }
}

extern "C" void kernel_launch(void* const* d_in, const int* in_sizes, int n_in,
                              void* d_out, int out_size, void* d_ws, size_t ws_size,
                              hipStream_t stream) {
    const float* x     = (const float*)d_in[0];
    const float* W_ih0 = (const float*)d_in[1];
    const float* W_hh0 = (const float*)d_in[2];
    const float* b_ih0 = (const float*)d_in[3];
    const float* b_hh0 = (const float*)d_in[4];
    const float* W_ih1 = (const float*)d_in[5];
    const float* W_hh1 = (const float*)d_in[6];
    const float* b_ih1 = (const float*)d_in[7];
    const float* b_hh1 = (const float*)d_in[8];
    const float* W_fc  = (const float*)d_in[9];
    const float* b_fc  = (const float*)d_in[10];
    float* out = (float*)d_out;

    dim3 grid(4096 / BT);   // 256 blocks = 1/CU
    dim3 block(NTHR);       // 8 waves
    lstm_mfma<<<grid, block, 0, stream>>>(x, W_ih0, W_hh0, b_ih0, b_hh0,
                                          W_ih1, W_hh1, b_ih1, b_hh1,
                                          W_fc, b_fc, out);
}

// Round 2
// 369.100 us; speedup vs baseline: 1.1082x; 1.0189x over previous
//
#include <hip/hip_runtime.h>

// 2-layer LSTM (H=50, B=4096, T=512, D_in=1) + FC(50->1), fused MFMA, round 16.
//
// = round-15 (layer-specialized waves, gate pre-scaling, merged-rcp cell, f16
// weights/h, 1 barrier/iter) with the wave count raised 8 -> 16 (1024 thr).
// r15 rocprof: 908 VALU-issue cyc/SIMD/iter at 55.6% busy == static cost of
// 6.5 cell_updates (7 trans ops @ ~16cyc each) -> VALU-issue-bound with 44%
// unfillable stall at 2 waves/SIMD. Total VALU work is fixed (26 updates/iter,
// trans count already minimal), so this round adds TLP only: 26 jobs over 16
// waves (NJ<=2), 4 waves/SIMD, per-SIMD update load {7,6,6,7} unchanged.
// LDS reads rise to 48 b128/iter (~576 cyc/CU) - still under the ~900-cyc
// VALU floor, so LDS stays sub-critical.
// Barrier counts identical on all wave paths (514); semantics unchanged.
// B-frag layout (r2-r13-verified): k -> ks=k>>5, lane=((k>>3)&3)*16+n, j=k&7.

#define TT 512
#define HH 50
#define BT 16
#define NTHR 1024  // 16 waves
#define L2E 1.44269504f

typedef _Float16 half8 __attribute__((ext_vector_type(8)));
typedef float floatx4 __attribute__((ext_vector_type(4)));

static __device__ __forceinline__ float fexp2(float x) { return __builtin_amdgcn_exp2f(x); }
static __device__ __forceinline__ float frcp(float x)  { return __builtin_amdgcn_rcpf(x); }

// PRE-SCALED cell update: inputs are already s_g*gate (s = -log2e, -log2e,
// -2log2e, -log2e for i,f,g,o), i.e. Ei=exp2(gi') = e^-i etc.
// c' = sig(f)*c + sig(i)*tanh(g) = R*[c*(1+Ei)(1+Eg) + (1-Eg)(1+Ef)],
// R = rcp((1+Ef)(1+Ei)(1+Eg)); h = sig(o)*tanh(c'), c clamped (NaN guard).
static __device__ __forceinline__ float cell_update(float gi, float gf, float gg,
                                                    float go, float& c) {
    float Ei = fexp2(gi);
    float Eg = fexp2(gg);
    float Ef = fexp2(gf);
    float p1 = (1.0f + Ei) * (1.0f + Eg);
    float fe = 1.0f + Ef;
    float R  = frcp(fe * p1);
    c = R * (c * p1 + (1.0f - Eg) * fe);
    float cl = fminf(fmaxf(c, -18.0f), 18.0f);
    float Eo = fexp2(go);
    float Ec = fexp2(cl * (-2.0f * L2E));
    float Ro = frcp((1.0f + Eo) * (1.0f + Ec));
    return (1.0f - Ec) * Ro;
}

#define MFMA(a, b, c) __builtin_amdgcn_mfma_f32_16x16x32_f16((a), (b), (c), 0, 0, 0)

// ---------------- layer-0 waves: NJ tile-jobs, tiles tbase..tbase+NJ-1 ----------------
template<int NJ>
static __device__ __forceinline__ void run_l0(
    int tbase, int ln, _Float16 (*Hf)[2048], const float* xs,
    const float* __restrict__ W_ih0, const float* __restrict__ W_hh0,
    const float* __restrict__ b_ih0, const float* __restrict__ b_hh0)
{
    const int m = ln & 15, q = ln >> 4;
    const float GSC[4] = { -L2E, -L2E, -2.0f * L2E, -L2E };

    half8 a0[NJ][2];
    float cc0[NJ][4], bw0[NJ][4], c[NJ];
    int   widx[NJ];
#pragma unroll
    for (int j = 0; j < NJ; ++j) {
        const int  tau  = tbase + j;
        const int  uA   = 4 * tau + (m >> 2);
        const int  gA   = m & 3;
        const bool rokA = (uA < HH);
        const int  wrow = gA * HH + uA;
        const float sA  = GSC[gA];
#pragma unroll
        for (int ks = 0; ks < 2; ++ks) {
            half8 h8;
#pragma unroll
            for (int jj = 0; jj < 8; ++jj) {
                int k = ks * 32 + q * 8 + jj;
                float w = (rokA && k < HH) ? W_hh0[wrow * HH + k] : 0.f;
                h8[jj] = (_Float16)(sA * w);
            }
            a0[j][ks] = h8;
        }
        const int  uC = 4 * tau + q;     // dummy units 50/51 -> zero-wt K slots
        const bool vC = (uC < HH);
#pragma unroll
        for (int g = 0; g < 4; ++g) {
            int rg = g * HH + (vC ? uC : 0);
            cc0[j][g] = vC ? GSC[g] * (b_ih0[rg] + b_hh0[rg]) : 0.f;
            bw0[j][g] = vC ? GSC[g] * W_ih0[rg] : 0.f;
        }
        const int kh = uC & 63;
        widx[j] = ((kh >> 5) * 64 + ((kh >> 3) & 3) * 16 + m) * 8 + (kh & 7);
        c[j] = 0.f;
    }

    __syncthreads();                       // staging (xs, Hf zero) complete

    // ---- t = 0: h1(0) depends on x only (h=0) -> write buf 1 ----
    {
        const float xv = xs[m];
#pragma unroll
        for (int j = 0; j < NJ; ++j) {
            float h = cell_update(cc0[j][0] + bw0[j][0] * xv, cc0[j][1] + bw0[j][1] * xv,
                                  cc0[j][2] + bw0[j][2] * xv, cc0[j][3] + bw0[j][3] * xv,
                                  c[j]);
            Hf[1][widx[j]] = (_Float16)h;
        }
        __syncthreads();
    }

#define ITER0(ttv, P)                                                       \
    {                                                                       \
        half8 b0 = *(const half8*)&Hf[(P)][(0 * 64 + ln) * 8];              \
        half8 b1 = *(const half8*)&Hf[(P)][(1 * 64 + ln) * 8];              \
        const float xv = xs[(ttv) * BT + m];                                \
        floatx4 acc[NJ];                                                    \
        _Pragma("unroll")                                                   \
        for (int j = 0; j < NJ; ++j) {                                      \
            floatx4 a;                                                      \
            _Pragma("unroll")                                               \
            for (int g = 0; g < 4; ++g) a[g] = cc0[j][g] + bw0[j][g] * xv;  \
            a = MFMA(a0[j][0], b0, a);                                      \
            a = MFMA(a0[j][1], b1, a);                                      \
            acc[j] = a;                                                     \
        }                                                                   \
        _Pragma("unroll")                                                   \
        for (int j = 0; j < NJ; ++j) {                                      \
            float h = cell_update(acc[j][0], acc[j][1], acc[j][2], acc[j][3], c[j]); \
            Hf[(P) ^ 1][widx[j]] = (_Float16)h;                             \
        }                                                                   \
        __syncthreads();                                                    \
    }

    for (int k = 1; k <= 255; ++k) {
        ITER0(2 * k - 1, 1);
        ITER0(2 * k, 0);
    }
    ITER0(511, 1);
    __syncthreads();                       // ttv = 512: L1-only step, barrier match
#undef ITER0
}

// ---------------- layer-1 waves: NJ tile-jobs, tiles tbase..tbase+NJ-1 ----------------
template<int NJ>
static __device__ __forceinline__ void run_l1(
    int tbase, int ln, _Float16 (*Hf)[2048],
    const float* __restrict__ W_ih1, const float* __restrict__ W_hh1,
    const float* __restrict__ b_ih1, const float* __restrict__ b_hh1)
{
    const int m = ln & 15, q = ln >> 4;
    const float GSC[4] = { -L2E, -L2E, -2.0f * L2E, -L2E };

    half8 a1[NJ][4];                       // [W_ih1 | pad | W_hh1 | pad] over K=128
    float cc1[NJ][4], c[NJ];
    int   widx[NJ];
#pragma unroll
    for (int j = 0; j < NJ; ++j) {
        const int  tau  = tbase + j;
        const int  uA   = 4 * tau + (m >> 2);
        const int  gA   = m & 3;
        const bool rokA = (uA < HH);
        const int  wrow = gA * HH + uA;
        const float sA  = GSC[gA];
#pragma unroll
        for (int ks = 0; ks < 4; ++ks) {
            half8 h8;
#pragma unroll
            for (int jj = 0; jj < 8; ++jj) {
                int k = ks * 32 + q * 8 + jj;
                float w = 0.f;
                if (rokA) {
                    if (k < HH)                      w = W_ih1[wrow * HH + k];
                    else if (k >= 64 && k < 64 + HH) w = W_hh1[wrow * HH + (k - 64)];
                }
                h8[jj] = (_Float16)(sA * w);
            }
            a1[j][ks] = h8;
        }
        const int  uC = 4 * tau + q;
        const bool vC = (uC < HH);
#pragma unroll
        for (int g = 0; g < 4; ++g) {
            int rg = g * HH + (vC ? uC : 0);
            cc1[j][g] = vC ? GSC[g] * (b_ih1[rg] + b_hh1[rg]) : 0.f;
        }
        const int kh = uC & 63;
        widx[j] = ((kh >> 5) * 64 + ((kh >> 3) & 3) * 16 + m) * 8 + (kh & 7) + 1024;
        c[j] = 0.f;
    }

    __syncthreads();                       // staging complete
    __syncthreads();                       // t=0 prologue: no L1 work (h2(-1)=0)

#define ITER1(P)                                                            \
    {                                                                       \
        half8 b0 = *(const half8*)&Hf[(P)][(0 * 64 + ln) * 8];              \
        half8 b1 = *(const half8*)&Hf[(P)][(1 * 64 + ln) * 8];              \
        half8 b2 = *(const half8*)&Hf[(P)][(2 * 64 + ln) * 8];              \
        half8 b3 = *(const half8*)&Hf[(P)][(3 * 64 + ln) * 8];              \
        floatx4 acc[NJ];                                                    \
        _Pragma("unroll")                                                   \
        for (int j = 0; j < NJ; ++j) {                                      \
            floatx4 a;                                                      \
            _Pragma("unroll")                                               \
            for (int g = 0; g < 4; ++g) a[g] = cc1[j][g];                   \
            a = MFMA(a1[j][0], b0, a);                                      \
            a = MFMA(a1[j][1], b1, a);                                      \
            a = MFMA(a1[j][2], b2, a);                                      \
            a = MFMA(a1[j][3], b3, a);                                      \
            acc[j] = a;                                                     \
        }                                                                   \
        _Pragma("unroll")                                                   \
        for (int j = 0; j < NJ; ++j) {                                      \
            float h = cell_update(acc[j][0], acc[j][1], acc[j][2], acc[j][3], c[j]); \
            Hf[(P) ^ 1][widx[j]] = (_Float16)h;                             \
        }                                                                   \
        __syncthreads();                                                    \
    }

    for (int k = 1; k <= 255; ++k) {
        ITER1(1);                          // ttv = 2k-1 -> computes t = ttv-1
        ITER1(0);                          // ttv = 2k
    }
    ITER1(1);                              // ttv = 511
    ITER1(0);                              // ttv = 512 -> h2(511) -> buf 1
#undef ITER1
}

__global__ __launch_bounds__(NTHR, 4) void lstm_mfma(
    const float* __restrict__ x,
    const float* __restrict__ W_ih0, const float* __restrict__ W_hh0,
    const float* __restrict__ b_ih0, const float* __restrict__ b_hh0,
    const float* __restrict__ W_ih1, const float* __restrict__ W_hh1,
    const float* __restrict__ b_ih1, const float* __restrict__ b_hh1,
    const float* __restrict__ W_fc,  const float* __restrict__ b_fc,
    float* __restrict__ out)
{
    __shared__ __align__(16) _Float16 Hf[2][2048];   // [buf][(ks*64+lane)*8+j]
    __shared__ float xs[TT * BT];

    const int tid = threadIdx.x;
    const int ln  = tid & 63;
    const int wv  = tid >> 6;              // 0..15
    const int b0g = blockIdx.x * BT;

    // ---------------- one-time staging ----------------
    for (int i = tid; i < BT * TT; i += NTHR) {
        int b = i & 15, t = i >> 4;
        xs[t * BT + b] = x[(size_t)(b0g + b) * TT + t];
    }
    for (int i = tid; i < 2 * 2048; i += NTHR) ((_Float16*)Hf)[i] = (_Float16)0.f;

    // job split (13 L0 jobs on waves 0-7, 13 L1 jobs on waves 8-15), chosen so
    // round-robin wave->SIMD (wv&3) gives per-SIMD update counts {7,6,6,7}:
    //   L0: w0:2@0 w1:2@2 w2:2@4 w3:2@6 w4:2@8 w5:1@10 w6:1@11 w7:1@12
    //   L1: w8:1@0 w9:1@1 w10:1@2 w11:2@3 w12:2@5 w13:2@7 w14:2@9 w15:2@11
    if (wv < 8) {
        if (wv < 5)
            run_l0<2>(2 * wv, ln, Hf, xs, W_ih0, W_hh0, b_ih0, b_hh0);
        else
            run_l0<1>(10 + (wv - 5), ln, Hf, xs, W_ih0, W_hh0, b_ih0, b_hh0);
    } else {
        const int w = wv - 8;
        if (w < 3)
            run_l1<1>(w, ln, Hf, W_ih1, W_hh1, b_ih1, b_hh1);
        else
            run_l1<2>(3 + 2 * (w - 3), ln, Hf, W_ih1, W_hh1, b_ih1, b_hh1);
    }

    // ---------------- FC epilogue: h2(511) in buf 1, slots k = 64+u ----------------
    if (tid < BT) {
        float a = b_fc[0];
        for (int u = 0; u < HH; ++u) {
            int k = 64 + u;
            int idx = ((k >> 5) * 64 + ((k >> 3) & 3) * 16 + tid) * 8 + (k & 7);
            a = fmaf((float)Hf[1][idx], W_fc[u], a);
        }
        out[b0g + tid] = a;
    }
}

extern "C" void kernel_launch(void* const* d_in, const int* in_sizes, int n_in,
                              void* d_out, int out_size, void* d_ws, size_t ws_size,
                              hipStream_t stream) {
    const float* x     = (const float*)d_in[0];
    const float* W_ih0 = (const float*)d_in[1];
    const float* W_hh0 = (const float*)d_in[2];
    const float* b_ih0 = (const float*)d_in[3];
    const float* b_hh0 = (const float*)d_in[4];
    const float* W_ih1 = (const float*)d_in[5];
    const float* W_hh1 = (const float*)d_in[6];
    const float* b_ih1 = (const float*)d_in[7];
    const float* b_hh1 = (const float*)d_in[8];
    const float* W_fc  = (const float*)d_in[9];
    const float* b_fc  = (const float*)d_in[10];
    float* out = (float*)d_out;

    dim3 grid(4096 / BT);   // 256 blocks = 1/CU
    dim3 block(NTHR);       // 16 waves
    lstm_mfma<<<grid, block, 0, stream>>>(x, W_ih0, W_hh0, b_ih0, b_hh0,
                                          W_ih1, W_hh1, b_ih1, b_hh1,
                                          W_fc, b_fc, out);
}

// Round 3
// 364.509 us; speedup vs baseline: 1.1222x; 1.0126x over previous
//
#include <hip/hip_runtime.h>

// 2-layer LSTM (H=50, B=4096, T=512, D_in=1) + FC(50->1), fused MFMA, round 17.
//
// = round-16 (16 layer-specialized waves, gate pre-scaling, merged-rcp cell)
// + two changes attacking the ~620 cyc/iter barrier-phase-lock idle that TLP
// could not fill (r16: 2->4 waves/SIMD gained only 2%):
//
// 1) LAG-2 L1: L1 computes h2(s-2) at iter s. Its h1 operand was written two
//    barriers ago -> L1 PREFETCHES its h1 B-frags (p0,p1) before the barrier,
//    overlapping L0's update phase. Post-barrier L1 starts MFMAs immediately
//    (no LDS wait); post-barrier LDS burst drops 48->32 b128 reads. This
//    de-phases the two wave groups (producer-consumer pipeline).
// 2) x/BIAS IN K-SLOTS: h1-region slot 50 == 1.0 (A carries GSC*bias row),
//    slot 51 == x(t) (A carries GSC*W_ih0 row). Dummy-unit h-writes (uC=50,51)
//    redirected to slots 52/53 (zero-A). All acc chains start from a hoisted
//    ZERO quad -> no per-iter acc-init movs, no cc/bw registers, no xs
//    broadcast read (one writer wave maintains the x slot).
//
// Buffers: H1 ring[4] (h1 units 0..49 + bias@50 + x@51 + dummies 52/53),
// H2 ring[2] (h2 units + dummies). Barrier count identical on all wave
// paths (516). B-frag layout (r2-r13-verified):
// k -> ks=k>>5, lane=((k>>3)&3)*16+n, j=k&7.

#define TT 512
#define HH 50
#define BT 16
#define NTHR 1024  // 16 waves
#define L2E 1.44269504f

typedef _Float16 half8 __attribute__((ext_vector_type(8)));
typedef float floatx4 __attribute__((ext_vector_type(4)));

static __device__ __forceinline__ float fexp2(float x) { return __builtin_amdgcn_exp2f(x); }
static __device__ __forceinline__ float frcp(float x)  { return __builtin_amdgcn_rcpf(x); }

// PRE-SCALED cell update: inputs are already s_g*gate (s = -log2e, -log2e,
// -2log2e, -log2e for i,f,g,o), i.e. Ei=exp2(gi') = e^-i etc.
// c' = sig(f)*c + sig(i)*tanh(g) = R*[c*(1+Ei)(1+Eg) + (1-Eg)(1+Ef)],
// R = rcp((1+Ef)(1+Ei)(1+Eg)); h = sig(o)*tanh(c'), c clamped (NaN guard).
static __device__ __forceinline__ float cell_update(float gi, float gf, float gg,
                                                    float go, float& c) {
    float Ei = fexp2(gi);
    float Eg = fexp2(gg);
    float Ef = fexp2(gf);
    float p1 = (1.0f + Ei) * (1.0f + Eg);
    float fe = 1.0f + Ef;
    float R  = frcp(fe * p1);
    c = R * (c * p1 + (1.0f - Eg) * fe);
    float cl = fminf(fmaxf(c, -18.0f), 18.0f);
    float Eo = fexp2(go);
    float Ec = fexp2(cl * (-2.0f * L2E));
    float Ro = frcp((1.0f + Eo) * (1.0f + Ec));
    return (1.0f - Ec) * Ro;
}

#define MFMA(a, b, c) __builtin_amdgcn_mfma_f32_16x16x32_f16((a), (b), (c), 0, 0, 0)

// ---------------- layer-0 waves: NJ tile-jobs, tiles tbase..tbase+NJ-1 ----------------
// Iter s computes h1(s) from h1(s-1) = H1[(s-1)&3]; writes H1[s&3].
// WRITER wave maintains x slot 51 of H1[s&3] with x(s+1).
template<int NJ, bool WRITER>
static __device__ __forceinline__ void run_l0(
    int tbase, int ln, _Float16 (*H1)[1024], const float* xs,
    const float* __restrict__ W_ih0, const float* __restrict__ W_hh0,
    const float* __restrict__ b_ih0, const float* __restrict__ b_hh0)
{
    const int m = ln & 15, q = ln >> 4;
    const float GSC[4] = { -L2E, -L2E, -2.0f * L2E, -L2E };

    half8 a0[NJ][2];
    float c[NJ];
    int   widx[NJ];
#pragma unroll
    for (int j = 0; j < NJ; ++j) {
        const int  tau  = tbase + j;
        const int  uA   = 4 * tau + (m >> 2);
        const int  gA   = m & 3;
        const bool rokA = (uA < HH);
        const int  wrow = gA * HH + uA;
        const float sA  = GSC[gA];
#pragma unroll
        for (int ks = 0; ks < 2; ++ks) {
            half8 h8;
#pragma unroll
            for (int jj = 0; jj < 8; ++jj) {
                int k = ks * 32 + q * 8 + jj;
                float w = 0.f;
                if (rokA) {
                    if (k < HH)       w = W_hh0[wrow * HH + k];
                    else if (k == 50) w = b_ih0[wrow] + b_hh0[wrow];
                    else if (k == 51) w = W_ih0[wrow];      // W_ih0 is [4H x 1]
                }
                h8[jj] = (_Float16)(sA * w);
            }
            a0[j][ks] = h8;
        }
        const int uC = 4 * tau + q;
        const int kh = (uC < HH) ? uC : (uC + 2);   // dummies 50,51 -> 52,53
        widx[j] = ((kh >> 5) * 64 + ((kh >> 3) & 3) * 16 + m) * 8 + (kh & 7);
        c[j] = 0.f;
    }

    __syncthreads();                       // A: staging + special slots visible

    // ---- t = 0: h1(0) from x(0) only (h=0), scalar path -> H1[0] ----
    {
        const float xv = xs[m];
#pragma unroll
        for (int j = 0; j < NJ; ++j) {
            const int  uC = 4 * (tbase + j) + q;
            const bool vC = (uC < HH);
            float g4[4];
#pragma unroll
            for (int g = 0; g < 4; ++g) {
                int rg = g * HH + (vC ? uC : 0);
                g4[g] = vC ? GSC[g] * ((b_ih0[rg] + b_hh0[rg]) + W_ih0[rg] * xv) : 0.f;
            }
            float h = cell_update(g4[0], g4[1], g4[2], g4[3], c[j]);
            H1[0][widx[j]] = (_Float16)h;
        }
    }
    __syncthreads();                       // B

    const floatx4 ZERO = { 0.f, 0.f, 0.f, 0.f };
    for (int s = 1; s <= 513; ++s) {
        if (s <= 511) {
            const _Float16* bufR = H1[(s - 1) & 3];
            _Float16*       bufW = H1[s & 3];
            half8 b0 = *(const half8*)&bufR[(0  + ln) * 8];
            half8 b1 = *(const half8*)&bufR[(64 + ln) * 8];
            floatx4 acc[NJ];
#pragma unroll
            for (int j = 0; j < NJ; ++j) {
                floatx4 a = MFMA(a0[j][0], b0, ZERO);
                acc[j] = MFMA(a0[j][1], b1, a);
            }
#pragma unroll
            for (int j = 0; j < NJ; ++j) {
                float h = cell_update(acc[j][0], acc[j][1], acc[j][2], acc[j][3], c[j]);
                bufW[widx[j]] = (_Float16)h;
            }
            if (WRITER) {
                if (ln < 16)               // x(s+1) -> slot 51; s=511 reads zero pad
                    bufW[(96 + ln) * 8 + 3] = (_Float16)xs[(s + 1) * BT + ln];
            }
        }
        __syncthreads();
    }
}

// ---------------- layer-1 waves: NJ tile-jobs, tiles tbase..tbase+NJ-1 ----------------
// Iter s computes h2(s-2) from h1(s-2) (PREFETCHED last iter into p0,p1) and
// h2(s-3) = H2[(s-1)&1]; writes H2[s&1]. End of iter prefetches h1(s-1).
template<int NJ>
static __device__ __forceinline__ void run_l1(
    int tbase, int ln, _Float16 (*H1)[1024], _Float16 (*H2)[1024],
    const float* __restrict__ W_ih1, const float* __restrict__ W_hh1,
    const float* __restrict__ b_ih1, const float* __restrict__ b_hh1)
{
    const int m = ln & 15, q = ln >> 4;
    const float GSC[4] = { -L2E, -L2E, -2.0f * L2E, -L2E };

    half8 a1[NJ][4];       // virtual K=128: [W_ih1 | bias@50 | 0 | W_hh1@64.. | 0]
    float c[NJ];
    int   widx[NJ];
#pragma unroll
    for (int j = 0; j < NJ; ++j) {
        const int  tau  = tbase + j;
        const int  uA   = 4 * tau + (m >> 2);
        const int  gA   = m & 3;
        const bool rokA = (uA < HH);
        const int  wrow = gA * HH + uA;
        const float sA  = GSC[gA];
#pragma unroll
        for (int ks = 0; ks < 4; ++ks) {
            half8 h8;
#pragma unroll
            for (int jj = 0; jj < 8; ++jj) {
                int k = ks * 32 + q * 8 + jj;
                float w = 0.f;
                if (rokA) {
                    if (k < HH)                      w = W_ih1[wrow * HH + k];
                    else if (k == 50)                w = b_ih1[wrow] + b_hh1[wrow];
                    else if (k >= 64 && k < 64 + HH) w = W_hh1[wrow * HH + (k - 64)];
                }
                h8[jj] = (_Float16)(sA * w);
            }
            a1[j][ks] = h8;
        }
        const int uC = 4 * tau + q;
        const int kh = (uC < HH) ? uC : (uC + 2);   // dummies -> 52,53 (zero-A)
        widx[j] = ((kh >> 5) * 64 + ((kh >> 3) & 3) * 16 + m) * 8 + (kh & 7);
        c[j] = 0.f;
    }

    __syncthreads();                       // A
    __syncthreads();                       // B (L0 prologue)

    half8 p0 = {}, p1 = {};                // prefetched h1 B-frags
    const floatx4 ZERO = { 0.f, 0.f, 0.f, 0.f };
    for (int s = 1; s <= 513; ++s) {
        if (s >= 2) {
            const _Float16* h2R = H2[(s - 1) & 1];
            _Float16*       h2W = H2[s & 1];
            half8 b2 = *(const half8*)&h2R[(0  + ln) * 8];
            half8 b3 = *(const half8*)&h2R[(64 + ln) * 8];
            floatx4 acc[NJ];
#pragma unroll
            for (int j = 0; j < NJ; ++j) {
                floatx4 a = MFMA(a1[j][0], p0, ZERO);   // no LDS wait: p0/p1 in regs
                a = MFMA(a1[j][1], p1, a);
                a = MFMA(a1[j][2], b2, a);
                acc[j] = MFMA(a1[j][3], b3, a);
            }
#pragma unroll
            for (int j = 0; j < NJ; ++j) {
                float h = cell_update(acc[j][0], acc[j][1], acc[j][2], acc[j][3], c[j]);
                h2W[widx[j]] = (_Float16)h;
            }
        }
        {   // prefetch h1(s-1) for next iter (valid: written before barrier(s-1))
            const _Float16* h1R = H1[(s - 1) & 3];
            p0 = *(const half8*)&h1R[(0  + ln) * 8];
            p1 = *(const half8*)&h1R[(64 + ln) * 8];
        }
        __syncthreads();
    }
}

__global__ __launch_bounds__(NTHR, 4) void lstm_mfma(
    const float* __restrict__ x,
    const float* __restrict__ W_ih0, const float* __restrict__ W_hh0,
    const float* __restrict__ b_ih0, const float* __restrict__ b_hh0,
    const float* __restrict__ W_ih1, const float* __restrict__ W_hh1,
    const float* __restrict__ b_ih1, const float* __restrict__ b_hh1,
    const float* __restrict__ W_fc,  const float* __restrict__ b_fc,
    float* __restrict__ out)
{
    __shared__ __align__(16) _Float16 H1[4][1024];   // h1 ring + bias/x slots
    __shared__ __align__(16) _Float16 H2[2][1024];   // h2 ring
    __shared__ float xs[(TT + 1) * BT];              // +1 zero pad row

    const int tid = threadIdx.x;
    const int ln  = tid & 63;
    const int wv  = tid >> 6;              // 0..15
    const int b0g = blockIdx.x * BT;

    // ---------------- one-time staging ----------------
    for (int i = tid; i < BT * TT; i += NTHR) {
        int b = i & 15, t = i >> 4;
        xs[t * BT + b] = x[(size_t)(b0g + b) * TT + t];
    }
    if (tid < BT) xs[TT * BT + tid] = 0.f;
    for (int i = tid; i < 4 * 1024; i += NTHR) ((_Float16*)H1)[i] = (_Float16)0.f;
    for (int i = tid; i < 2 * 1024; i += NTHR) ((_Float16*)H2)[i] = (_Float16)0.f;
    __syncthreads();
    if (tid < 16) {
        // bias slot k=50 (ks=1, lane 32+n, j=2) == 1.0, all 4 ring buffers
#pragma unroll
        for (int r = 0; r < 4; ++r) H1[r][(96 + tid) * 8 + 2] = (_Float16)1.0f;
        // x(1) -> slot k=51 of H1[0] (read by L0 at s=1)
        H1[0][(96 + tid) * 8 + 3] = (_Float16)xs[BT + tid];
    }
    // (visibility of the above: covered by run_*'s first __syncthreads)

    // job split (13 L0 jobs on waves 0-7, 13 L1 jobs on waves 8-15), chosen so
    // round-robin wave->SIMD (wv&3) gives per-SIMD update counts {7,6,6,7}:
    //   L0: w0:2@0 w1:2@2 w2:2@4 w3:2@6 w4:2@8 w5:1@10 w6:1@11 w7:1@12(writer)
    //   L1: w8:1@0 w9:1@1 w10:1@2 w11:2@3 w12:2@5 w13:2@7 w14:2@9 w15:2@11
    if (wv < 8) {
        if (wv < 5)
            run_l0<2, false>(2 * wv, ln, H1, xs, W_ih0, W_hh0, b_ih0, b_hh0);
        else if (wv < 7)
            run_l0<1, false>(10 + (wv - 5), ln, H1, xs, W_ih0, W_hh0, b_ih0, b_hh0);
        else
            run_l0<1, true>(12, ln, H1, xs, W_ih0, W_hh0, b_ih0, b_hh0);
    } else {
        const int w = wv - 8;
        if (w < 3)
            run_l1<1>(w, ln, H1, H2, W_ih1, W_hh1, b_ih1, b_hh1);
        else
            run_l1<2>(3 + 2 * (w - 3), ln, H1, H2, W_ih1, W_hh1, b_ih1, b_hh1);
    }

    // -------- FC epilogue: h2(511) written at iter 513 -> H2[1] --------
    if (tid < BT) {
        float a = b_fc[0];
        for (int u = 0; u < HH; ++u) {
            int idx = ((u >> 5) * 64 + ((u >> 3) & 3) * 16 + tid) * 8 + (u & 7);
            a = fmaf((float)H2[1][idx], W_fc[u], a);
        }
        out[b0g + tid] = a;
    }
}

extern "C" void kernel_launch(void* const* d_in, const int* in_sizes, int n_in,
                              void* d_out, int out_size, void* d_ws, size_t ws_size,
                              hipStream_t stream) {
    const float* x     = (const float*)d_in[0];
    const float* W_ih0 = (const float*)d_in[1];
    const float* W_hh0 = (const float*)d_in[2];
    const float* b_ih0 = (const float*)d_in[3];
    const float* b_hh0 = (const float*)d_in[4];
    const float* W_ih1 = (const float*)d_in[5];
    const float* W_hh1 = (const float*)d_in[6];
    const float* b_ih1 = (const float*)d_in[7];
    const float* b_hh1 = (const float*)d_in[8];
    const float* W_fc  = (const float*)d_in[9];
    const float* b_fc  = (const float*)d_in[10];
    float* out = (float*)d_out;

    dim3 grid(4096 / BT);   // 256 blocks = 1/CU
    dim3 block(NTHR);       // 16 waves
    lstm_mfma<<<grid, block, 0, stream>>>(x, W_ih0, W_hh0, b_ih0, b_hh0,
                                          W_ih1, W_hh1, b_ih1, b_hh1,
                                          W_fc, b_fc, out);
}